// Round 3
// baseline (763.907 us; speedup 1.0000x reference)
//
#include <hip/hip_runtime.h>
#include <math.h>

#define B_ 512
#define S_ 2048
#define E_DIM 64
#define P_DIM 32
#define H_DIM 64

__device__ __forceinline__ float wave_reduce_sum(float v) {
#pragma unroll
  for (int m = 32; m >= 1; m >>= 1) v += __shfl_xor(v, m, 64);
  return v;
}

__device__ __forceinline__ float wave_reduce_max(float v) {
#pragma unroll
  for (int m = 32; m >= 1; m >>= 1) v = fmaxf(v, __shfl_xor(v, m, 64));
  return v;
}

__device__ __forceinline__ float tanh_fast(float x) {
  float e = __expf(2.0f * x);
  return 1.0f - 2.0f * __builtin_amdgcn_rcpf(e + 1.0f);
}

// ---------------------------------------------------------------------------
// K1: a[b,s] = sum_h tanh(c[b,h] + items[b,s,:]@We[:,h] + pos[b,s,:]@Wp[:,h]
//                          + bias[h]) * z[h]
// Grid: B_ * 8 blocks of 256 (one position per thread).
// Lane = position: X row register-cached (96 VGPR), weights wave-uniform ->
// scalar loads (s_load), no LDS traffic in the hot loop, no wave reduces.
// ---------------------------------------------------------------------------
__global__ __launch_bounds__(256, 3) void scores_kernel(
    const float* __restrict__ seq_items, const float* __restrict__ seq_pos,
    const float* __restrict__ target_item, const float* __restrict__ Wp,
    const float* __restrict__ We, const float* __restrict__ Wc,
    const float* __restrict__ bias, const float* __restrict__ z,
    const int* __restrict__ seq_len, float* __restrict__ a_out) {
  const int blk = blockIdx.x;
  const int b = blk >> 3;
  const int s0 = (blk & 7) << 8;
  const int L = seq_len[b];
  if (s0 >= L) return;

  __shared__ float c_sh[64];
  const int tid = threadIdx.x;

  // wave 0: c[b,h] = bias[h] + target[b,:] @ Wc[:,h]   (lane = h, coalesced)
  if (tid < 64) {
    const int h = tid;
    float c = bias[h];
    const float* __restrict__ tg = target_item + b * 64;
#pragma unroll
    for (int e = 0; e < 64; ++e) c = fmaf(tg[e], Wc[e * H_DIM + h], c);
    c_sh[h] = c;
  }
  __syncthreads();

  const int s = s0 + tid;
  if (s < L) {  // tail waves with exec==0 skip the whole body
    const float* __restrict__ rowI = seq_items + ((size_t)b * S_ + s) * E_DIM;
    const float* __restrict__ rowP = seq_pos + ((size_t)b * S_ + s) * P_DIM;

    float xi[E_DIM], xp[P_DIM];
#pragma unroll
    for (int i = 0; i < E_DIM / 4; ++i) {
      const float4 v = ((const float4*)rowI)[i];
      xi[4 * i + 0] = v.x; xi[4 * i + 1] = v.y;
      xi[4 * i + 2] = v.z; xi[4 * i + 3] = v.w;
    }
#pragma unroll
    for (int i = 0; i < P_DIM / 4; ++i) {
      const float4 v = ((const float4*)rowP)[i];
      xp[4 * i + 0] = v.x; xp[4 * i + 1] = v.y;
      xp[4 * i + 2] = v.z; xp[4 * i + 3] = v.w;
    }

    float a = 0.0f;
#pragma unroll 2
    for (int h = 0; h < H_DIM; ++h) {
      // weights at wave-uniform addresses -> scalar loads
      float acc0 = c_sh[h], acc1 = 0.0f, acc2 = 0.0f, acc3 = 0.0f;
#pragma unroll
      for (int e = 0; e < 16; ++e) {
        acc0 = fmaf(xi[e +  0], We[(e +  0) * H_DIM + h], acc0);
        acc1 = fmaf(xi[e + 16], We[(e + 16) * H_DIM + h], acc1);
        acc2 = fmaf(xi[e + 32], We[(e + 32) * H_DIM + h], acc2);
        acc3 = fmaf(xi[e + 48], We[(e + 48) * H_DIM + h], acc3);
      }
#pragma unroll
      for (int p = 0; p < 8; ++p) {
        acc0 = fmaf(xp[p +  0], Wp[(p +  0) * H_DIM + h], acc0);
        acc1 = fmaf(xp[p +  8], Wp[(p +  8) * H_DIM + h], acc1);
        acc2 = fmaf(xp[p + 16], Wp[(p + 16) * H_DIM + h], acc2);
        acc3 = fmaf(xp[p + 24], Wp[(p + 24) * H_DIM + h], acc3);
      }
      const float pre = (acc0 + acc1) + (acc2 + acc3);
      a = fmaf(tanh_fast(pre), z[h], a);
    }
    a_out[(size_t)b * S_ + s] = a;
  }
}

// ---------------------------------------------------------------------------
// K2: per-b softmax over a[b,0:L]; writes w in-place, r, zeroes out_u.
// L==0 -> uniform w = 1/S, r = 0.  Grid: B_ blocks of 256.
// ---------------------------------------------------------------------------
__global__ __launch_bounds__(256) void softmax_kernel(
    float* __restrict__ a_buf, const int* __restrict__ seq_len,
    float* __restrict__ out) {
  __shared__ float red[4];
  const int b = blockIdx.x;
  const int tid = threadIdx.x;
  const int wv = tid >> 6;
  const int L = seq_len[b];
  float* __restrict__ out_u = out;
  float* __restrict__ out_r = out + B_ * E_DIM;

  if (tid < 64) out_u[b * E_DIM + tid] = 0.0f;  // K3 accumulates atomically

  float* __restrict__ a = a_buf + (size_t)b * S_;

  if (L == 0) {
    const float inv = 1.0f / (float)S_;
    for (int s = tid; s < S_; s += 256) a[s] = inv;
    if (tid == 0) out_r[b] = 0.0f;
    return;
  }

  float av[8];
  float mx = -INFINITY, sa = 0.0f;
#pragma unroll
  for (int i = 0; i < 8; ++i) {
    const int s = tid + 256 * i;
    if (s < L) {
      const float x = a[s];
      av[i] = x;
      mx = fmaxf(mx, x);
      sa += x;
    } else {
      av[i] = 0.0f;
    }
  }
  mx = wave_reduce_max(mx);
  if ((tid & 63) == 0) red[wv] = mx;
  __syncthreads();
  const float m = fmaxf(fmaxf(red[0], red[1]), fmaxf(red[2], red[3]));
  __syncthreads();

  float se = 0.0f;
  float ev[8];
#pragma unroll
  for (int i = 0; i < 8; ++i) {
    const int s = tid + 256 * i;
    if (s < L) {
      const float e = __expf(av[i] - m);
      ev[i] = e;
      se += e;
    } else {
      ev[i] = 0.0f;
    }
  }
  se = wave_reduce_sum(se);
  if ((tid & 63) == 0) red[wv] = se;
  __syncthreads();
  const float l = red[0] + red[1] + red[2] + red[3];
  __syncthreads();
  sa = wave_reduce_sum(sa);
  if ((tid & 63) == 0) red[wv] = sa;
  __syncthreads();
  const float r = red[0] + red[1] + red[2] + red[3];

  const float invl = 1.0f / l;
#pragma unroll
  for (int i = 0; i < 8; ++i) {
    const int s = tid + 256 * i;
    a[s] = (s < L) ? ev[i] * invl : 0.0f;
  }
  if (tid == 0) out_r[b] = r;
}

// ---------------------------------------------------------------------------
// K3: u[b,:] += sum_s w[b,s] * items[b,s,:] over a 256-position chunk.
// Grid: B_ * 8 blocks of 256. lane%16 = float4 column, lane/16 = row.
// ---------------------------------------------------------------------------
__global__ __launch_bounds__(256) void wsum_kernel(
    const float* __restrict__ seq_items, const float* __restrict__ w_buf,
    const int* __restrict__ seq_len, float* __restrict__ out) {
  const int blk = blockIdx.x;
  const int b = blk >> 3;
  const int c = blk & 7;
  const int s0 = c << 8;
  const int L = seq_len[b];
  const int Leff = (L == 0) ? S_ : L;
  if (s0 >= Leff) return;
  const int send = min(s0 + 256, Leff);

  const int tid = threadIdx.x;
  const int e4 = tid & 15;
  const int row = tid >> 4;

  const float4* __restrict__ items4 =
      (const float4*)(seq_items + (size_t)b * S_ * E_DIM);
  const float* __restrict__ w = w_buf + (size_t)b * S_;

  float4 acc = make_float4(0.f, 0.f, 0.f, 0.f);
#pragma unroll 4
  for (int s = s0 + row; s < send; s += 16) {
    const float ww = w[s];
    const float4 x = items4[s * 16 + e4];
    acc.x = fmaf(ww, x.x, acc.x);
    acc.y = fmaf(ww, x.y, acc.y);
    acc.z = fmaf(ww, x.z, acc.z);
    acc.w = fmaf(ww, x.w, acc.w);
  }

  __shared__ float4 red[256];
  red[tid] = acc;
  __syncthreads();
  if (tid < 16) {
    float4 sacc = red[tid];
#pragma unroll
    for (int i = 1; i < 16; ++i) {
      const float4 t2 = red[i * 16 + tid];
      sacc.x += t2.x; sacc.y += t2.y; sacc.z += t2.z; sacc.w += t2.w;
    }
    float* dst = out + b * E_DIM + tid * 4;
    atomicAdd(dst + 0, sacc.x);
    atomicAdd(dst + 1, sacc.y);
    atomicAdd(dst + 2, sacc.z);
    atomicAdd(dst + 3, sacc.w);
  }
}

extern "C" void kernel_launch(void* const* d_in, const int* in_sizes, int n_in,
                              void* d_out, int out_size, void* d_ws, size_t ws_size,
                              hipStream_t stream) {
  const float* seq_items = (const float*)d_in[0];
  const float* seq_pos = (const float*)d_in[1];
  const float* target_item = (const float*)d_in[2];
  const float* Wp = (const float*)d_in[3];
  const float* We = (const float*)d_in[4];
  const float* Wc = (const float*)d_in[5];
  const float* bias = (const float*)d_in[6];
  const float* z = (const float*)d_in[7];
  const int* seq_len = (const int*)d_in[8];
  float* out = (float*)d_out;
  float* a_buf = (float*)d_ws;  // B_*S_ floats = 4 MB

  scores_kernel<<<B_ * 8, 256, 0, stream>>>(
      seq_items, seq_pos, target_item, Wp, We, Wc, bias, z, seq_len, a_buf);
  softmax_kernel<<<B_, 256, 0, stream>>>(a_buf, seq_len, out);
  wsum_kernel<<<B_ * 8, 256, 0, stream>>>(seq_items, a_buf, seq_len, out);
}

// Round 4
// 467.572 us; speedup vs baseline: 1.6338x; 1.6338x over previous
//
#include <hip/hip_runtime.h>
#include <math.h>

#define B_ 512
#define S_ 2048
#define E_DIM 64
#define P_DIM 32
#define H_DIM 64

typedef short s16x8 __attribute__((ext_vector_type(8)));
typedef float f32x4 __attribute__((ext_vector_type(4)));

__device__ __forceinline__ float wave_reduce_sum(float v) {
#pragma unroll
  for (int m = 32; m >= 1; m >>= 1) v += __shfl_xor(v, m, 64);
  return v;
}

__device__ __forceinline__ float wave_reduce_max(float v) {
#pragma unroll
  for (int m = 32; m >= 1; m >>= 1) v = fmaxf(v, __shfl_xor(v, m, 64));
  return v;
}

__device__ __forceinline__ float tanh_fast(float x) {
  float e = __expf(2.0f * x);
  return 1.0f - 2.0f * __builtin_amdgcn_rcpf(e + 1.0f);
}

// fp32 -> bf16 bits with round-to-nearest-even
__device__ __forceinline__ short bf16b(float x) {
  union { float f; unsigned u; } a;
  a.f = x;
  unsigned r = (a.u + 0x7FFFu + ((a.u >> 16) & 1u)) >> 16;
  return (short)r;
}

// ---------------------------------------------------------------------------
// K1 (MFMA): a[b,s] = sum_h tanh(c[b,h] + [items|pos]@[We;Wp][:,h]) * z[h]
// 128 positions per block, 4 waves x 2 M-tiles(16 rows), K=96 in 3 steps of 32.
// A: global->VGPR in fragment layout (lane: m=l&15, k=(l>>4)*8+j), fp32->bf16.
// B: built once per block into LDS (12 frags), then register-resident.
// C/D: col=lane&15, row=(lane>>4)*4+reg (m89-verified mapping).
// ---------------------------------------------------------------------------
__global__ __launch_bounds__(256) void scores_mfma_kernel(
    const float* __restrict__ seq_items, const float* __restrict__ seq_pos,
    const float* __restrict__ target_item, const float* __restrict__ Wp,
    const float* __restrict__ We, const float* __restrict__ Wc,
    const float* __restrict__ bias, const float* __restrict__ z,
    const int* __restrict__ seq_len, float* __restrict__ a_out) {
  const int blk = blockIdx.x;
  const int b = blk >> 4;          // 16 tiles of 128 positions per b
  const int s0 = (blk & 15) << 7;
  const int L = seq_len[b];
  if (s0 >= L) return;  // rows >= L are ignored by K2 (writes zeros there)

  __shared__ s16x8 lds_b[12 * 64];   // 12 KiB: B fragments
  __shared__ float c_part[4 * 64];   // partial c over e-slices

  const int tid = threadIdx.x;
  const int l = tid & 63;
  const int w = tid >> 6;
  const int cc = l & 15;  // col within 16 (n / h-within-tile; also row m for A)
  const int q = l >> 4;   // quad -> k-chunk (and row-group for C/D)

  // ---- build B fragments: wave w builds frags 3w..3w+2 ----
  // frag f: kstep = f>>2 (0,1: We rows kstep*32..+31; 2: Wp), ntile = f&3.
  // lane l holds B[k=(l>>4)*8+j][n=ntile*16+(l&15)], j=0..7.
#pragma unroll
  for (int i = 0; i < 3; ++i) {
    const int f = w * 3 + i;
    const int kstep = f >> 2;
    const int nt = f & 3;
    const float* __restrict__ src =
        (kstep < 2) ? (We + (size_t)(kstep * 32 + q * 8) * H_DIM + nt * 16 + cc)
                    : (Wp + (size_t)(q * 8) * H_DIM + nt * 16 + cc);
    s16x8 v;
#pragma unroll
    for (int j = 0; j < 8; ++j) v[j] = bf16b(src[(size_t)j * H_DIM]);
    lds_b[f * 64 + l] = v;
  }

  // ---- partial c[b,h]: wave w covers e in [16w,16w+16); wave0 adds bias ----
  {
    const float* __restrict__ tg = target_item + b * 64;
    float cp = (w == 0) ? bias[l] : 0.0f;
#pragma unroll
    for (int e = 0; e < 16; ++e)
      cp = fmaf(tg[w * 16 + e], Wc[(w * 16 + e) * H_DIM + l], cp);
    c_part[w * 64 + l] = cp;
  }
  __syncthreads();

  s16x8 bfr[12];
#pragma unroll
  for (int f = 0; f < 12; ++f) bfr[f] = lds_b[f * 64 + l];

  float ch[4], zh[4];
#pragma unroll
  for (int nt = 0; nt < 4; ++nt) {
    const int h = nt * 16 + cc;
    ch[nt] = c_part[h] + c_part[64 + h] + c_part[128 + h] + c_part[192 + h];
    zh[nt] = z[h];
  }

  const float* __restrict__ itemsB = seq_items + (size_t)b * S_ * E_DIM;
  const float* __restrict__ posB = seq_pos + (size_t)b * S_ * P_DIM;
  float* __restrict__ aB = a_out + (size_t)b * S_;

#pragma unroll
  for (int mt = 0; mt < 2; ++mt) {
    const int rb = s0 + w * 32 + mt * 16;  // row base of this 16-row M-tile
    const int s = rb + cc;                 // this lane's row (A: m = l&15)
    f32x4 acc[4] = {};                     // one C-frag per ntile

    // K-steps 0,1: items features [0..31], [32..63]
#pragma unroll
    for (int kk = 0; kk < 2; ++kk) {
      const float* __restrict__ p = itemsB + (size_t)s * E_DIM + kk * 32 + q * 8;
      const float4 x0 = ((const float4*)p)[0];
      const float4 x1 = ((const float4*)p)[1];
      s16x8 af;
      af[0] = bf16b(x0.x); af[1] = bf16b(x0.y);
      af[2] = bf16b(x0.z); af[3] = bf16b(x0.w);
      af[4] = bf16b(x1.x); af[5] = bf16b(x1.y);
      af[6] = bf16b(x1.z); af[7] = bf16b(x1.w);
#pragma unroll
      for (int nt = 0; nt < 4; ++nt)
        acc[nt] = __builtin_amdgcn_mfma_f32_16x16x32_bf16(af, bfr[kk * 4 + nt],
                                                          acc[nt], 0, 0, 0);
    }
    // K-step 2: pos features [0..31]
    {
      const float* __restrict__ p = posB + (size_t)s * P_DIM + q * 8;
      const float4 x0 = ((const float4*)p)[0];
      const float4 x1 = ((const float4*)p)[1];
      s16x8 af;
      af[0] = bf16b(x0.x); af[1] = bf16b(x0.y);
      af[2] = bf16b(x0.z); af[3] = bf16b(x0.w);
      af[4] = bf16b(x1.x); af[5] = bf16b(x1.y);
      af[6] = bf16b(x1.z); af[7] = bf16b(x1.w);
#pragma unroll
      for (int nt = 0; nt < 4; ++nt)
        acc[nt] = __builtin_amdgcn_mfma_f32_16x16x32_bf16(af, bfr[8 + nt],
                                                          acc[nt], 0, 0, 0);
    }

    // ---- epilogue: tanh + z, reduce over h (16 cols x 4 ntiles) ----
    float asum[4];
#pragma unroll
    for (int r = 0; r < 4; ++r) {
      float t = tanh_fast(acc[0][r] + ch[0]) * zh[0];
      t += tanh_fast(acc[1][r] + ch[1]) * zh[1];
      t += tanh_fast(acc[2][r] + ch[2]) * zh[2];
      t += tanh_fast(acc[3][r] + ch[3]) * zh[3];
      asum[r] = t;
    }
#pragma unroll
    for (int r = 0; r < 4; ++r) {
#pragma unroll
      for (int m = 8; m >= 1; m >>= 1) asum[r] += __shfl_xor(asum[r], m, 64);
    }
    if (cc == 0) {
#pragma unroll
      for (int r = 0; r < 4; ++r) aB[rb + q * 4 + r] = asum[r];
    }
  }
}

// ---------------------------------------------------------------------------
// K2: per-b softmax over a[b,0:L]; writes w in-place, r, zeroes out_u.
// L==0 -> uniform w = 1/S, r = 0.  Grid: B_ blocks of 256.
// ---------------------------------------------------------------------------
__global__ __launch_bounds__(256) void softmax_kernel(
    float* __restrict__ a_buf, const int* __restrict__ seq_len,
    float* __restrict__ out) {
  __shared__ float red[4];
  const int b = blockIdx.x;
  const int tid = threadIdx.x;
  const int wv = tid >> 6;
  const int L = seq_len[b];
  float* __restrict__ out_u = out;
  float* __restrict__ out_r = out + B_ * E_DIM;

  if (tid < 64) out_u[b * E_DIM + tid] = 0.0f;  // K3 accumulates atomically

  float* __restrict__ a = a_buf + (size_t)b * S_;

  if (L == 0) {
    const float inv = 1.0f / (float)S_;
    for (int s = tid; s < S_; s += 256) a[s] = inv;
    if (tid == 0) out_r[b] = 0.0f;
    return;
  }

  float av[8];
  float mx = -INFINITY, sa = 0.0f;
#pragma unroll
  for (int i = 0; i < 8; ++i) {
    const int s = tid + 256 * i;
    if (s < L) {
      const float x = a[s];
      av[i] = x;
      mx = fmaxf(mx, x);
      sa += x;
    } else {
      av[i] = 0.0f;
    }
  }
  mx = wave_reduce_max(mx);
  if ((tid & 63) == 0) red[wv] = mx;
  __syncthreads();
  const float m = fmaxf(fmaxf(red[0], red[1]), fmaxf(red[2], red[3]));
  __syncthreads();

  float se = 0.0f;
  float ev[8];
#pragma unroll
  for (int i = 0; i < 8; ++i) {
    const int s = tid + 256 * i;
    if (s < L) {
      const float e = __expf(av[i] - m);
      ev[i] = e;
      se += e;
    } else {
      ev[i] = 0.0f;
    }
  }
  se = wave_reduce_sum(se);
  if ((tid & 63) == 0) red[wv] = se;
  __syncthreads();
  const float l = red[0] + red[1] + red[2] + red[3];
  __syncthreads();
  sa = wave_reduce_sum(sa);
  if ((tid & 63) == 0) red[wv] = sa;
  __syncthreads();
  const float r = red[0] + red[1] + red[2] + red[3];

  const float invl = 1.0f / l;
#pragma unroll
  for (int i = 0; i < 8; ++i) {
    const int s = tid + 256 * i;
    a[s] = (s < L) ? ev[i] * invl : 0.0f;
  }
  if (tid == 0) out_r[b] = r;
}

// ---------------------------------------------------------------------------
// K3: u[b,:] += sum_s w[b,s] * items[b,s,:] over a 256-position chunk.
// Grid: B_ * 8 blocks of 256. lane%16 = float4 column, lane/16 = row.
// ---------------------------------------------------------------------------
__global__ __launch_bounds__(256) void wsum_kernel(
    const float* __restrict__ seq_items, const float* __restrict__ w_buf,
    const int* __restrict__ seq_len, float* __restrict__ out) {
  const int blk = blockIdx.x;
  const int b = blk >> 3;
  const int c = blk & 7;
  const int s0 = c << 8;
  const int L = seq_len[b];
  const int Leff = (L == 0) ? S_ : L;
  if (s0 >= Leff) return;
  const int send = min(s0 + 256, Leff);

  const int tid = threadIdx.x;
  const int e4 = tid & 15;
  const int row = tid >> 4;

  const float4* __restrict__ items4 =
      (const float4*)(seq_items + (size_t)b * S_ * E_DIM);
  const float* __restrict__ w = w_buf + (size_t)b * S_;

  float4 acc = make_float4(0.f, 0.f, 0.f, 0.f);
#pragma unroll 4
  for (int s = s0 + row; s < send; s += 16) {
    const float ww = w[s];
    const float4 x = items4[s * 16 + e4];
    acc.x = fmaf(ww, x.x, acc.x);
    acc.y = fmaf(ww, x.y, acc.y);
    acc.z = fmaf(ww, x.z, acc.z);
    acc.w = fmaf(ww, x.w, acc.w);
  }

  __shared__ float4 red[256];
  red[tid] = acc;
  __syncthreads();
  if (tid < 16) {
    float4 sacc = red[tid];
#pragma unroll
    for (int i = 1; i < 16; ++i) {
      const float4 t2 = red[i * 16 + tid];
      sacc.x += t2.x; sacc.y += t2.y; sacc.z += t2.z; sacc.w += t2.w;
    }
    float* dst = out + b * E_DIM + tid * 4;
    atomicAdd(dst + 0, sacc.x);
    atomicAdd(dst + 1, sacc.y);
    atomicAdd(dst + 2, sacc.z);
    atomicAdd(dst + 3, sacc.w);
  }
}

extern "C" void kernel_launch(void* const* d_in, const int* in_sizes, int n_in,
                              void* d_out, int out_size, void* d_ws, size_t ws_size,
                              hipStream_t stream) {
  const float* seq_items = (const float*)d_in[0];
  const float* seq_pos = (const float*)d_in[1];
  const float* target_item = (const float*)d_in[2];
  const float* Wp = (const float*)d_in[3];
  const float* We = (const float*)d_in[4];
  const float* Wc = (const float*)d_in[5];
  const float* bias = (const float*)d_in[6];
  const float* z = (const float*)d_in[7];
  const int* seq_len = (const int*)d_in[8];
  float* out = (float*)d_out;
  float* a_buf = (float*)d_ws;  // B_*S_ floats = 4 MB

  scores_mfma_kernel<<<B_ * 16, 256, 0, stream>>>(
      seq_items, seq_pos, target_item, Wp, We, Wc, bias, z, seq_len, a_buf);
  softmax_kernel<<<B_, 256, 0, stream>>>(a_buf, seq_len, out);
  wsum_kernel<<<B_ * 8, 256, 0, stream>>>(seq_items, a_buf, seq_len, out);
}